// Round 1
// 243.339 us; speedup vs baseline: 1.0008x; 1.0008x over previous
//
#include <hip/hip_runtime.h>
#include <stdint.h>

#define IN_DIM  32768
#define OUT_DIM 32768
#define BATCH   1024
#define NT      1024
#define ITER    (OUT_DIM / 4 / NT)   // 8 compute iters (4 outputs each)
#define SITER   (IN_DIM / 4 / NT)    // 8 stage iters (4 floats each)
#define RPB     2                    // rows per block (software-pipelined)
#define GRID    (BATCH / RPB)        // 512 blocks = exactly 2 resident per CU

typedef float fvec4 __attribute__((ext_vector_type(4)));

__device__ __forceinline__ uint32_t pack2_f16(float lo, float hi) {
    auto h = __builtin_amdgcn_cvt_pkrtz(lo, hi);   // v_cvt_pkrtz_f16_f32: 2 elems/instr
    return __builtin_bit_cast(uint32_t, h);
}
__device__ __forceinline__ float ldrow(const uint16_t* row, uint32_t byteoff) {
    _Float16 h = *(const _Float16*)((const char*)row + byteoff);
    return (float)h;
}
__device__ __forceinline__ float sel(uint32_t flag, float v) {
    return flag ? 1.0f - v : v;
}

// packed layout: low16 = (idx_a<<1) | flagA ; high16 = (idx_b<<1) | flagB
// idx<<1 is directly the LDS byte offset of the fp16 element.
__global__ void pack_meta(const int* __restrict__ idx_a,
                          const int* __restrict__ idx_b,
                          const float* __restrict__ logits,
                          uint32_t* __restrict__ packed) {
    int j = blockIdx.x * blockDim.x + threadIdx.x;
    if (j >= OUT_DIM) return;
    uint32_t ia = (((uint32_t)idx_a[j]) << 1) & 0xFFFFu;
    uint32_t ib = (((uint32_t)idx_b[j]) << 1) & 0xFFFFu;
    if (logits[2 * j + 0] > 0.0f) ia |= 1u;   // sigmoid(l)>0.5 <=> l>0
    if (logits[2 * j + 1] > 0.0f) ib |= 1u;
    packed[j] = ia | (ib << 16);
}

// 2 rows per block, software-pipelined: while computing row r0, the fp32 data
// of row r1 is prefetched into 32 VGPRs (one float4 chunk per compute iter).
// Meta load for iter i+1 is issued BEFORE prefetch chunk i, so the in-order
// vmcnt wait for meta never drains the prefetch stream (2-iter distance).
__global__ __launch_bounds__(NT, 8) void logic_gather(
        const float* __restrict__ x,
        const uint32_t* __restrict__ packed,
        float* __restrict__ out) {
    __shared__ __align__(16) uint16_t row[IN_DIM];  // 64 KiB fp16 row -> 2 blocks/CU
    const int t  = threadIdx.x;
    const int r0 = blockIdx.x;
    const int r1 = r0 + GRID;

    const uint4* __restrict__ pk    = (const uint4*)packed;
    uint2*       __restrict__ row64 = (uint2*)row;

    // ---- stage row r0 (the only fully-exposed stage in the block)
    {
        const float4* __restrict__ xr = (const float4*)(x + (size_t)r0 * IN_DIM);
#pragma unroll
        for (int i = 0; i < SITER; ++i) {
            float4 v = xr[i * NT + t];
            uint2 h;
            h.x = pack2_f16(v.x, v.y);
            h.y = pack2_f16(v.z, v.w);
            row64[i * NT + t] = h;
        }
    }
    __syncthreads();

    const float4* __restrict__ xr1 = (const float4*)(x + (size_t)r1 * IN_DIM);
    float4 pf0, pf1, pf2, pf3, pf4, pf5, pf6, pf7;   // 32 VGPR prefetch buffer

// One compute iteration: meta lookahead load, optional prefetch issue,
// 8 batched random LDS reads, selects + mul, nontemporal store.
#define STEP(i, orow, ...)                                                          \
    {                                                                               \
        uint4 p1 = ((i) + 1 < ITER) ? pk[((i) + 1) * NT + t] : p0;                  \
        __VA_ARGS__;                                                                \
        const uint32_t w0 = p0.x, w1 = p0.y, w2 = p0.z, w3 = p0.w;                  \
        float a0 = ldrow(row, w0 & 0xFFFEu), b0 = ldrow(row, (w0 >> 16) & 0xFFFEu); \
        float a1 = ldrow(row, w1 & 0xFFFEu), b1 = ldrow(row, (w1 >> 16) & 0xFFFEu); \
        float a2 = ldrow(row, w2 & 0xFFFEu), b2 = ldrow(row, (w2 >> 16) & 0xFFFEu); \
        float a3 = ldrow(row, w3 & 0xFFFEu), b3 = ldrow(row, (w3 >> 16) & 0xFFFEu); \
        fvec4 res;                                                                  \
        res.x = sel(w0 & 1u, a0) * sel(w0 & 0x10000u, b0);                          \
        res.y = sel(w1 & 1u, a1) * sel(w1 & 0x10000u, b1);                          \
        res.z = sel(w2 & 1u, a2) * sel(w2 & 0x10000u, b2);                          \
        res.w = sel(w3 & 1u, a3) * sel(w3 & 0x10000u, b3);                          \
        __builtin_nontemporal_store(res, &(orow)[(i) * NT + t]);                    \
        p0 = p1;                                                                    \
    }

    // ---- compute row r0, prefetching row r1 (sched_barrier pins one
    //      prefetch chunk per iteration: bounds VGPR pressure, keeps issue spread)
    {
        fvec4* __restrict__ o0 = (fvec4*)(out + (size_t)r0 * OUT_DIM);
        uint4 p0 = pk[t];
        STEP(0, o0, __builtin_amdgcn_sched_barrier(0); pf0 = xr1[0 * NT + t])
        STEP(1, o0, __builtin_amdgcn_sched_barrier(0); pf1 = xr1[1 * NT + t])
        STEP(2, o0, __builtin_amdgcn_sched_barrier(0); pf2 = xr1[2 * NT + t])
        STEP(3, o0, __builtin_amdgcn_sched_barrier(0); pf3 = xr1[3 * NT + t])
        STEP(4, o0, __builtin_amdgcn_sched_barrier(0); pf4 = xr1[4 * NT + t])
        STEP(5, o0, __builtin_amdgcn_sched_barrier(0); pf5 = xr1[5 * NT + t])
        STEP(6, o0, __builtin_amdgcn_sched_barrier(0); pf6 = xr1[6 * NT + t])
        STEP(7, o0, __builtin_amdgcn_sched_barrier(0); pf7 = xr1[7 * NT + t])
    }

    __syncthreads();   // all row-r0 LDS reads done; pf data landed (vmcnt drain)

    // ---- convert + write row r1 into LDS (cheap: 16 cvt_pkrtz + 8 ds_write_b64)
    {
        uint2 h;
        h.x = pack2_f16(pf0.x, pf0.y); h.y = pack2_f16(pf0.z, pf0.w); row64[0 * NT + t] = h;
        h.x = pack2_f16(pf1.x, pf1.y); h.y = pack2_f16(pf1.z, pf1.w); row64[1 * NT + t] = h;
        h.x = pack2_f16(pf2.x, pf2.y); h.y = pack2_f16(pf2.z, pf2.w); row64[2 * NT + t] = h;
        h.x = pack2_f16(pf3.x, pf3.y); h.y = pack2_f16(pf3.z, pf3.w); row64[3 * NT + t] = h;
        h.x = pack2_f16(pf4.x, pf4.y); h.y = pack2_f16(pf4.z, pf4.w); row64[4 * NT + t] = h;
        h.x = pack2_f16(pf5.x, pf5.y); h.y = pack2_f16(pf5.z, pf5.w); row64[5 * NT + t] = h;
        h.x = pack2_f16(pf6.x, pf6.y); h.y = pack2_f16(pf6.z, pf6.w); row64[6 * NT + t] = h;
        h.x = pack2_f16(pf7.x, pf7.y); h.y = pack2_f16(pf7.z, pf7.w); row64[7 * NT + t] = h;
    }
    __syncthreads();

    // ---- compute row r1 (no prefetch; compiler free to schedule)
    {
        fvec4* __restrict__ o1 = (fvec4*)(out + (size_t)r1 * OUT_DIM);
        uint4 p0 = pk[t];
        STEP(0, o1)
        STEP(1, o1)
        STEP(2, o1)
        STEP(3, o1)
        STEP(4, o1)
        STEP(5, o1)
        STEP(6, o1)
        STEP(7, o1)
    }
#undef STEP
}

extern "C" void kernel_launch(void* const* d_in, const int* in_sizes, int n_in,
                              void* d_out, int out_size, void* d_ws, size_t ws_size,
                              hipStream_t stream) {
    const float* x      = (const float*)d_in[0];
    const float* logits = (const float*)d_in[1];
    const int*   idx_a  = (const int*)d_in[2];
    const int*   idx_b  = (const int*)d_in[3];
    uint32_t*    packed = (uint32_t*)d_ws;   // 128 KiB scratch
    float*       out    = (float*)d_out;

    hipLaunchKernelGGL(pack_meta, dim3(OUT_DIM / 256), dim3(256), 0, stream,
                       idx_a, idx_b, logits, packed);
    hipLaunchKernelGGL(logic_gather, dim3(GRID), dim3(NT), 0, stream,
                       x, packed, out);
}